// Round 1
// baseline (1895.676 us; speedup 1.0000x reference)
//
#include <hip/hip_runtime.h>

// DoubleSin: out = mlp1(x) + mlp2(2x), each mlp = 1->64->64->64->1 with snake
// activation snake(p,a) = p + sin(a p)^2 / a.
//
// fp32 baseline: 1 thread = 1 point. h[64] in VGPRs. W2^T / W3^T staged in LDS
// ([j][i] layout so that for fixed input-chan j the 16 output accumulators read
// contiguous floats -> ds_read_b128 broadcast, conflict-free). Small params
// (w1,b,a,1/a,w4) also in LDS. Branches processed serially, re-staging LDS
// between them to stay under the 64KB static LDS limit (~35KB used).

#define HDIM 64

struct SmallP {
    float w1[HDIM], b1[HDIM], a1[HDIM], ra1[HDIM];
    float b2[HDIM], a2[HDIM], ra2[HDIM];
    float b3[HDIM], a3[HDIM], ra3[HDIM];
    float w4[HDIM];
    float b4;
};

__device__ __forceinline__ float snake1(float p, float a, float ra) {
    float t = __sinf(a * p);
    return fmaf(t * t, ra, p);
}

__device__ __forceinline__ void layer64(const float* __restrict__ wt,   // LDS [j][i]
                                        const float* __restrict__ b,
                                        const float* __restrict__ a,
                                        const float* __restrict__ ra,
                                        float (&h)[HDIM])
{
    float hn[HDIM];
    #pragma unroll
    for (int i0 = 0; i0 < HDIM; i0 += 16) {
        float acc[16];
        #pragma unroll
        for (int i = 0; i < 16; ++i) acc[i] = b[i0 + i];
        #pragma unroll
        for (int j = 0; j < HDIM; ++j) {
            const float hj = h[j];
            const float* row = wt + j * HDIM + i0;
            #pragma unroll
            for (int i = 0; i < 16; ++i) acc[i] = fmaf(hj, row[i], acc[i]);
        }
        #pragma unroll
        for (int i = 0; i < 16; ++i) hn[i0 + i] = snake1(acc[i], a[i0 + i], ra[i0 + i]);
    }
    #pragma unroll
    for (int i = 0; i < HDIM; ++i) h[i] = hn[i];
}

__global__ __launch_bounds__(256) void doublesin_kernel(
    const float* __restrict__ x,
    const float* __restrict__ W1a, const float* __restrict__ b1a, const float* __restrict__ a1a,
    const float* __restrict__ W2a, const float* __restrict__ b2a, const float* __restrict__ a2a,
    const float* __restrict__ W3a, const float* __restrict__ b3a, const float* __restrict__ a3a,
    const float* __restrict__ W4a, const float* __restrict__ b4a,
    const float* __restrict__ W1b, const float* __restrict__ b1b, const float* __restrict__ a1b,
    const float* __restrict__ W2b, const float* __restrict__ b2b, const float* __restrict__ a2b,
    const float* __restrict__ W3b, const float* __restrict__ b3b, const float* __restrict__ a3b,
    const float* __restrict__ W4b, const float* __restrict__ b4b,
    float* __restrict__ out, int n)
{
    __shared__ float w2t[HDIM * HDIM];
    __shared__ float w3t[HDIM * HDIM];
    __shared__ SmallP sp;

    const int tid = threadIdx.x;
    const int gid = blockIdx.x * 256 + tid;
    const float xv = (gid < n) ? x[gid] : 0.0f;
    float result = 0.0f;

    #pragma unroll 1
    for (int br = 0; br < 2; ++br) {
        const float* W1 = br ? W1b : W1a;
        const float* B1 = br ? b1b : b1a;
        const float* A1 = br ? a1b : a1a;
        const float* W2 = br ? W2b : W2a;
        const float* B2 = br ? b2b : b2a;
        const float* A2 = br ? a2b : a2a;
        const float* W3 = br ? W3b : W3a;
        const float* B3 = br ? b3b : b3a;
        const float* A3 = br ? a3b : a3a;
        const float* W4 = br ? W4b : W4a;
        const float* B4 = br ? b4b : b4a;

        __syncthreads();   // previous branch's LDS reads complete before restage
        for (int idx = tid; idx < HDIM * HDIM; idx += 256) {
            const int i = idx >> 6, j = idx & 63;     // W[i][j] -> wt[j][i]
            w2t[j * HDIM + i] = W2[idx];
            w3t[j * HDIM + i] = W3[idx];
        }
        if (tid < HDIM) {
            sp.w1[tid] = W1[tid];
            sp.b1[tid] = B1[tid]; sp.a1[tid] = A1[tid]; sp.ra1[tid] = 1.0f / A1[tid];
            sp.b2[tid] = B2[tid]; sp.a2[tid] = A2[tid]; sp.ra2[tid] = 1.0f / A2[tid];
            sp.b3[tid] = B3[tid]; sp.a3[tid] = A3[tid]; sp.ra3[tid] = 1.0f / A3[tid];
            sp.w4[tid] = W4[tid];
            if (tid == 0) sp.b4 = B4[0];
        }
        __syncthreads();

        const float xin = br ? (2.0f * xv) : xv;
        float h[HDIM];
        #pragma unroll
        for (int c = 0; c < HDIM; ++c) {
            const float p = fmaf(sp.w1[c], xin, sp.b1[c]);
            h[c] = snake1(p, sp.a1[c], sp.ra1[c]);
        }
        layer64(w2t, sp.b2, sp.a2, sp.ra2, h);
        layer64(w3t, sp.b3, sp.a3, sp.ra3, h);
        float acc = sp.b4;
        #pragma unroll
        for (int c = 0; c < HDIM; ++c) acc = fmaf(h[c], sp.w4[c], acc);
        result += acc;
    }

    if (gid < n) out[gid] = result;
}

extern "C" void kernel_launch(void* const* d_in, const int* in_sizes, int n_in,
                              void* d_out, int out_size, void* d_ws, size_t ws_size,
                              hipStream_t stream) {
    const float* x   = (const float*)d_in[0];
    const float* W1a = (const float*)d_in[1];
    const float* b1a = (const float*)d_in[2];
    const float* a1a = (const float*)d_in[3];
    const float* W2a = (const float*)d_in[4];
    const float* b2a = (const float*)d_in[5];
    const float* a2a = (const float*)d_in[6];
    const float* W3a = (const float*)d_in[7];
    const float* b3a = (const float*)d_in[8];
    const float* a3a = (const float*)d_in[9];
    const float* W4a = (const float*)d_in[10];
    const float* b4a = (const float*)d_in[11];
    const float* W1b = (const float*)d_in[12];
    const float* b1b = (const float*)d_in[13];
    const float* a1b = (const float*)d_in[14];
    const float* W2b = (const float*)d_in[15];
    const float* b2b = (const float*)d_in[16];
    const float* a2b = (const float*)d_in[17];
    const float* W3b = (const float*)d_in[18];
    const float* b3b = (const float*)d_in[19];
    const float* a3b = (const float*)d_in[20];
    const float* W4b = (const float*)d_in[21];
    const float* b4b = (const float*)d_in[22];

    const int n = in_sizes[0];
    const int grid = (n + 255) / 256;
    doublesin_kernel<<<grid, 256, 0, stream>>>(
        x,
        W1a, b1a, a1a, W2a, b2a, a2a, W3a, b3a, a3a, W4a, b4a,
        W1b, b1b, a1b, W2b, b2b, a2b, W3b, b3b, a3b, W4b, b4b,
        (float*)d_out, n);
}

// Round 2
// 398.673 us; speedup vs baseline: 4.7550x; 4.7550x over previous
//
#include <hip/hip_runtime.h>

// DoubleSin via bf16 MFMA (16x16x32), zero-LDS design.
//
// Swapped-operand scheme: D = W·H with W as A-operand (16 outch x 32 k) and
// activations as B-operand (32 k x 16 points).  With the gfx950 layouts
//   A/B: lane l -> col/row l&15, k = 4*(l>>4) + (j&3) + 16*(j>>2)
//   C/D: col = l&15 (point), row(outch within tile) = 4*(l>>4) + reg
// the post-activation D registers ARE the next layer's B fragment (elems 0-3
// <- tile 2s regs 0-3, elems 4-7 <- tile 2s+1 regs 0-3) -- no cross-lane ops,
// no LDS between layers.
//
// Snake param folding: q_L = a_L (.) (W_L h + b_L);  h_L = (q + sin^2 q)/a_L.
// Define g = q + sin^2 q (param-free) and fold the scales into the weights:
//   W_L' = diag(a_L) W_L diag(1/a_{L-1}),  bias' = a_L (.) b_L,
//   w4' = w4 (.) (1/a3).
//
// Precision: 3-term bf16 split (Whi*Hhi + Whi*Hlo + Wlo*Hhi) keeps error at
// ~2^-18 relative -- absmax should match the fp32 kernel (~0.004).
//
// Two launches: branch 1 writes out, branch 2 (input 2x) accumulates.

typedef __attribute__((ext_vector_type(8))) short bf8v;
typedef __attribute__((ext_vector_type(4))) float f4v;

__device__ __forceinline__ unsigned short f2bf(float f) {
    unsigned u = __builtin_bit_cast(unsigned, f);
    u += 0x7fffu + ((u >> 16) & 1u);          // round-to-nearest-even
    return (unsigned short)(u >> 16);
}
__device__ __forceinline__ float bf2f(unsigned short b) {
    return __builtin_bit_cast(float, (unsigned)b << 16);
}

#define MFMA(a, b, c) __builtin_amdgcn_mfma_f32_16x16x32_bf16((a), (b), (c), 0, 0, 0)

// activation g = q + sin^2(q) on all 16 accs, then build hi/lo B fragments
__device__ __forceinline__ void act_and_frags(f4v (&acc)[4], bf8v (&Bh)[2], bf8v (&Bl)[2]) {
    #pragma unroll
    for (int t = 0; t < 4; ++t) {
        #pragma unroll
        for (int j = 0; j < 4; ++j) {
            float q = acc[t][j];
            float s = __sinf(q);
            acc[t][j] = fmaf(s, s, q);
        }
    }
    #pragma unroll
    for (int s = 0; s < 2; ++s) {
        #pragma unroll
        for (int j = 0; j < 4; ++j) {
            float v0 = acc[2 * s][j];
            float v1 = acc[2 * s + 1][j];
            unsigned short h0 = f2bf(v0);
            unsigned short h1 = f2bf(v1);
            Bh[s][j]     = (short)h0;
            Bh[s][4 + j] = (short)h1;
            Bl[s][j]     = (short)f2bf(v0 - bf2f(h0));
            Bl[s][4 + j] = (short)f2bf(v1 - bf2f(h1));
        }
    }
}

__global__ __launch_bounds__(256, 2) void mlp_branch(
    const float* __restrict__ x,
    const float* __restrict__ W1, const float* __restrict__ b1, const float* __restrict__ a1,
    const float* __restrict__ W2, const float* __restrict__ b2, const float* __restrict__ a2,
    const float* __restrict__ W3, const float* __restrict__ b3, const float* __restrict__ a3,
    const float* __restrict__ W4, const float* __restrict__ b4,
    float* __restrict__ out, int n, float xscale, int accum)
{
    const int lane = threadIdx.x & 63;
    const int col  = lane & 15;          // point within tile / outch within A-row
    const int g    = lane >> 4;          // lane group 0..3
    const int wid  = (int)((blockIdx.x * blockDim.x + threadIdx.x) >> 6);
    const int nwaves = (int)((gridDim.x * blockDim.x) >> 6);
    const int ntiles = n >> 4;

    const bf8v z8 = {0, 0, 0, 0, 0, 0, 0, 0};

    // ---------------- preamble: build weight fragments (per lane) ----------
    // Layer 1: A1[t] cols: k=0 -> a1*w1, k=1 -> a1*b1 (only lane group 0)
    bf8v A1hi[4], A1lo[4];
    #pragma unroll
    for (int t = 0; t < 4; ++t) {
        const int o = 16 * t + col;
        const float av = a1[o];
        const float w1p = av * W1[o];
        const float b1p = av * b1[o];
        unsigned short wh = f2bf(w1p), bh = f2bf(b1p);
        unsigned short wl = f2bf(w1p - bf2f(wh)), bl = f2bf(b1p - bf2f(bh));
        bf8v h = z8, l = z8;
        h[0] = (short)wh; h[1] = (short)bh;
        l[0] = (short)wl; l[1] = (short)bl;
        A1hi[t] = (g == 0) ? h : z8;
        A1lo[t] = (g == 0) ? l : z8;
    }

    // Layers 2,3: W'[o][k] = aout[o] * W[o][k] / ain[k]
    bf8v W2h[4][2], W2l[4][2], W3h[4][2], W3l[4][2];
    #pragma unroll
    for (int L = 0; L < 2; ++L) {
        const float* W    = L ? W3 : W2;
        const float* aout = L ? a3 : a2;
        const float* ain  = L ? a2 : a1;
        #pragma unroll
        for (int s = 0; s < 2; ++s) {
            const int kb = 32 * s + 4 * g;
            const f4v aia = *(const f4v*)(ain + kb);
            const f4v aib = *(const f4v*)(ain + kb + 16);
            float ra[8];
            #pragma unroll
            for (int j = 0; j < 4; ++j) { ra[j] = 1.0f / aia[j]; ra[4 + j] = 1.0f / aib[j]; }
            #pragma unroll
            for (int t = 0; t < 4; ++t) {
                const int o = 16 * t + col;
                const f4v wa = *(const f4v*)(W + o * 64 + kb);
                const f4v wb = *(const f4v*)(W + o * 64 + kb + 16);
                const float ao = aout[o];
                bf8v hh = z8, ll = z8;
                #pragma unroll
                for (int j = 0; j < 8; ++j) {
                    const float wv = (j < 4) ? wa[j & 3] : wb[j & 3];
                    const float wp = ao * wv * ra[j];
                    unsigned short hb = f2bf(wp);
                    hh[j] = (short)hb;
                    ll[j] = (short)f2bf(wp - bf2f(hb));
                }
                if (L == 0) { W2h[t][s] = hh; W2l[t][s] = ll; }
                else        { W3h[t][s] = hh; W3l[t][s] = ll; }
            }
        }
    }

    // biases (scaled) and w4' = w4 / a3; per-lane channel quad = 16t + 4g + r
    f4v bias2[4], bias3[4], w4p[4];
    #pragma unroll
    for (int t = 0; t < 4; ++t) {
        const int c0 = 16 * t + 4 * g;
        const f4v b2v = *(const f4v*)(b2 + c0);
        const f4v a2v = *(const f4v*)(a2 + c0);
        const f4v b3v = *(const f4v*)(b3 + c0);
        const f4v a3v = *(const f4v*)(a3 + c0);
        const f4v w4v = *(const f4v*)(W4 + c0);
        bias2[t] = b2v * a2v;
        bias3[t] = b3v * a3v;
        w4p[t]   = w4v / a3v;
    }
    const float b4v = b4[0];

    // ---------------- main loop over point tiles (16 points each) ----------
    int tile = wid;
    if (tile >= ntiles) return;
    float xc = xscale * x[tile * 16 + col];
    float oc = accum ? out[tile * 16 + col] : 0.0f;

    while (tile < ntiles) {
        const int tnext = tile + nwaves;
        float xn = 0.0f, on = 0.0f;
        if (tnext < ntiles) {
            xn = xscale * x[tnext * 16 + col];
            if (accum) on = out[tnext * 16 + col];
        }

        // ---- layer 1: q1 = A1 · [x; 1] ----
        unsigned short xh = f2bf(xc);
        float xres = xc - bf2f(xh);
        unsigned short xl = f2bf(xres);
        bf8v B1h = z8, B1l = z8;
        if (g == 0) {
            B1h[0] = (short)xh; B1h[1] = (short)0x3F80;   // 1.0 bf16
            B1l[0] = (short)xl;
        }
        f4v acc[4];
        #pragma unroll
        for (int t = 0; t < 4; ++t) {
            f4v d = {0.0f, 0.0f, 0.0f, 0.0f};
            d = MFMA(A1hi[t], B1h, d);
            d = MFMA(A1hi[t], B1l, d);
            d = MFMA(A1lo[t], B1h, d);
            acc[t] = d;
        }

        bf8v Bh[2], Bl[2];
        act_and_frags(acc, Bh, Bl);    // g1 -> fragments

        // ---- layer 2 ----
        f4v acc2[4];
        #pragma unroll
        for (int t = 0; t < 4; ++t) {
            f4v d = bias2[t];
            #pragma unroll
            for (int s = 0; s < 2; ++s) {
                d = MFMA(W2h[t][s], Bh[s], d);
                d = MFMA(W2h[t][s], Bl[s], d);
                d = MFMA(W2l[t][s], Bh[s], d);
            }
            acc2[t] = d;
        }
        act_and_frags(acc2, Bh, Bl);   // g2 -> fragments

        // ---- layer 3 ----
        #pragma unroll
        for (int t = 0; t < 4; ++t) {
            f4v d = bias3[t];
            #pragma unroll
            for (int s = 0; s < 2; ++s) {
                d = MFMA(W3h[t][s], Bh[s], d);
                d = MFMA(W3h[t][s], Bl[s], d);
                d = MFMA(W3l[t][s], Bh[s], d);
            }
            acc[t] = d;
        }
        // g3 (no fragment build needed)
        #pragma unroll
        for (int t = 0; t < 4; ++t) {
            #pragma unroll
            for (int j = 0; j < 4; ++j) {
                float q = acc[t][j];
                float s = __sinf(q);
                acc[t][j] = fmaf(s, s, q);
            }
        }

        // ---- layer 4: out = sum w4' (.) g3 + b4 ----
        float p = 0.0f;
        #pragma unroll
        for (int t = 0; t < 4; ++t) {
            #pragma unroll
            for (int j = 0; j < 4; ++j) p = fmaf(w4p[t][j], acc[t][j], p);
        }
        p += __shfl_xor(p, 16);
        p += __shfl_xor(p, 32);

        const float res = p + b4v + oc;
        if (lane < 16) out[tile * 16 + col] = res;

        tile = tnext; xc = xn; oc = on;
    }
}

extern "C" void kernel_launch(void* const* d_in, const int* in_sizes, int n_in,
                              void* d_out, int out_size, void* d_ws, size_t ws_size,
                              hipStream_t stream) {
    const float* x   = (const float*)d_in[0];
    const float* W1a = (const float*)d_in[1];
    const float* b1a = (const float*)d_in[2];
    const float* a1a = (const float*)d_in[3];
    const float* W2a = (const float*)d_in[4];
    const float* b2a = (const float*)d_in[5];
    const float* a2a = (const float*)d_in[6];
    const float* W3a = (const float*)d_in[7];
    const float* b3a = (const float*)d_in[8];
    const float* a3a = (const float*)d_in[9];
    const float* W4a = (const float*)d_in[10];
    const float* b4a = (const float*)d_in[11];
    const float* W1b = (const float*)d_in[12];
    const float* b1b = (const float*)d_in[13];
    const float* a1b = (const float*)d_in[14];
    const float* W2b = (const float*)d_in[15];
    const float* b2b = (const float*)d_in[16];
    const float* a2b = (const float*)d_in[17];
    const float* W3b = (const float*)d_in[18];
    const float* b3b = (const float*)d_in[19];
    const float* a3b = (const float*)d_in[20];
    const float* W4b = (const float*)d_in[21];
    const float* b4b = (const float*)d_in[22];

    const int n = in_sizes[0];
    float* out = (float*)d_out;

    mlp_branch<<<512, 256, 0, stream>>>(x, W1a, b1a, a1a, W2a, b2a, a2a,
                                        W3a, b3a, a3a, W4a, b4a,
                                        out, n, 1.0f, 0);
    mlp_branch<<<512, 256, 0, stream>>>(x, W1b, b1b, a1b, W2b, b2b, a2b,
                                        W3b, b3b, a3b, W4b, b4b,
                                        out, n, 2.0f, 1);
}

// Round 4
// 308.925 us; speedup vs baseline: 6.1364x; 1.2905x over previous
//
#include <hip/hip_runtime.h>

// DoubleSin via bf16 MFMA (16x16x32), zero-LDS.
// Round-4 = round-3 with the compile fix: pack conversions via inline-asm
// v_cvt_pk_bf16_f32 (the HIP __hip_bfloat162 type is not trivially copyable,
// so __builtin_bit_cast was rejected).
//  - layer 1 (rank-2) computed in fp32 VALU (16 fma) instead of 12 MFMAs
//  - act->fragment conversion: 1 cvt_pk for hi pair, unpack+sub for residuals,
//    1 cvt_pk for lo pair  (~6 VALU ops/pair vs ~14 scalar-RNE before)
//  - accum flag is a template parameter.
// Structure: D = W'.H (weights as A-operand); D registers of layer L are
// exactly the B fragment of layer L+1 (no cross-lane traffic). Snake scales
// folded into weights: W_L' = diag(a_L) W_L diag(1/a_{L-1}); activation is
// param-free g(q) = q + sin^2(q). 3-term bf16 split Wh*Bh + Wh*Bl + Wl*Bh.

typedef __attribute__((ext_vector_type(8))) short bf8v;
typedef __attribute__((ext_vector_type(4))) float f4v;

union BF8U { bf8v v; unsigned d[4]; unsigned short s[8]; };

__device__ __forceinline__ unsigned short f2bf(float f) {   // preamble only
    unsigned u = __builtin_bit_cast(unsigned, f);
    u += 0x7fffu + ((u >> 16) & 1u);
    return (unsigned short)(u >> 16);
}
__device__ __forceinline__ float bf2f(unsigned short b) {
    return __builtin_bit_cast(float, (unsigned)b << 16);
}
__device__ __forceinline__ unsigned cvt_pk_bf16(float lo, float hi) {
    unsigned r;
    asm("v_cvt_pk_bf16_f32 %0, %1, %2" : "=v"(r) : "v"(lo), "v"(hi));
    return r;
}

#define MFMA(a, b, c) __builtin_amdgcn_mfma_f32_16x16x32_bf16((a), (b), (c), 0, 0, 0)

// g(q) = q + sin^2 q on all 16 accs, then build hi/lo B fragments via cvt_pk
__device__ __forceinline__ void act_and_frags(f4v (&acc)[4], bf8v (&Bh)[2], bf8v (&Bl)[2]) {
    #pragma unroll
    for (int t = 0; t < 4; ++t) {
        #pragma unroll
        for (int j = 0; j < 4; ++j) {
            float q = acc[t][j];
            float s = __sinf(q);
            acc[t][j] = fmaf(s, s, q);
        }
    }
    #pragma unroll
    for (int s2 = 0; s2 < 2; ++s2) {
        BF8U h, l;
        #pragma unroll
        for (int p = 0; p < 4; ++p) {
            const int t = 2 * s2 + (p >> 1);
            const int j0 = (p & 1) * 2;
            const float v0 = acc[t][j0], v1 = acc[t][j0 + 1];
            const unsigned hd = cvt_pk_bf16(v0, v1);      // lo16=bf(v0), hi16=bf(v1)
            h.d[p] = hd;
            const float r0 = v0 - __builtin_bit_cast(float, hd << 16);
            const float r1 = v1 - __builtin_bit_cast(float, hd & 0xffff0000u);
            l.d[p] = cvt_pk_bf16(r0, r1);
        }
        Bh[s2] = h.v; Bl[s2] = l.v;
    }
}

template <int ACCUM>
__global__ __launch_bounds__(256, 2) void mlp_branch(
    const float* __restrict__ x,
    const float* __restrict__ W1, const float* __restrict__ b1, const float* __restrict__ a1,
    const float* __restrict__ W2, const float* __restrict__ b2, const float* __restrict__ a2,
    const float* __restrict__ W3, const float* __restrict__ b3, const float* __restrict__ a3,
    const float* __restrict__ W4, const float* __restrict__ b4,
    float* __restrict__ out, int n, float xscale)
{
    const int lane = threadIdx.x & 63;
    const int col  = lane & 15;
    const int g    = lane >> 4;
    const int wid  = (int)((blockIdx.x * blockDim.x + threadIdx.x) >> 6);
    const int nwaves = (int)((gridDim.x * blockDim.x) >> 6);
    const int ntiles = n >> 4;

    const bf8v z8 = {0, 0, 0, 0, 0, 0, 0, 0};

    // ---------------- preamble: fold params, build weight fragments --------
    // Layer 1 (VALU): q1[ch] = (a1*W1)[ch] * x + (a1*b1)[ch], ch = 16t+4g+j
    f4v w1p[4], b1p[4];
    #pragma unroll
    for (int t = 0; t < 4; ++t) {
        const int c0 = 16 * t + 4 * g;
        const f4v a1v = *(const f4v*)(a1 + c0);
        w1p[t] = a1v * *(const f4v*)(W1 + c0);
        b1p[t] = a1v * *(const f4v*)(b1 + c0);
    }

    // Layers 2,3 fragments: W'[o][k] = aout[o] * W[o][k] / ain[k]
    bf8v W2h[4][2], W2l[4][2], W3h[4][2], W3l[4][2];
    #pragma unroll
    for (int L = 0; L < 2; ++L) {
        const float* W    = L ? W3 : W2;
        const float* aout = L ? a3 : a2;
        const float* ain  = L ? a2 : a1;
        #pragma unroll
        for (int s = 0; s < 2; ++s) {
            const int kb = 32 * s + 4 * g;
            const f4v aia = *(const f4v*)(ain + kb);
            const f4v aib = *(const f4v*)(ain + kb + 16);
            float ra[8];
            #pragma unroll
            for (int j = 0; j < 4; ++j) { ra[j] = 1.0f / aia[j]; ra[4 + j] = 1.0f / aib[j]; }
            #pragma unroll
            for (int t = 0; t < 4; ++t) {
                const int o = 16 * t + col;
                const f4v wa = *(const f4v*)(W + o * 64 + kb);
                const f4v wb = *(const f4v*)(W + o * 64 + kb + 16);
                const float ao = aout[o];
                bf8v hh = z8, ll = z8;
                #pragma unroll
                for (int j = 0; j < 8; ++j) {
                    const float wv = (j < 4) ? wa[j & 3] : wb[j & 3];
                    const float wp = ao * wv * ra[j];
                    unsigned short hb = f2bf(wp);
                    hh[j] = (short)hb;
                    ll[j] = (short)f2bf(wp - bf2f(hb));
                }
                if (L == 0) { W2h[t][s] = hh; W2l[t][s] = ll; }
                else        { W3h[t][s] = hh; W3l[t][s] = ll; }
            }
        }
    }

    // scaled biases and w4' = w4 / a3 (per-lane quad = 16t + 4g + j)
    f4v bias2[4], bias3[4], w4p[4];
    #pragma unroll
    for (int t = 0; t < 4; ++t) {
        const int c0 = 16 * t + 4 * g;
        bias2[t] = *(const f4v*)(b2 + c0) * *(const f4v*)(a2 + c0);
        bias3[t] = *(const f4v*)(b3 + c0) * *(const f4v*)(a3 + c0);
        w4p[t]   = *(const f4v*)(W4 + c0) / *(const f4v*)(a3 + c0);
    }
    const float b4v = b4[0];

    // ---------------- main loop over 16-point tiles ------------------------
    int tile = wid;
    if (tile >= ntiles) return;
    float xc = xscale * x[tile * 16 + col];
    float oc = ACCUM ? out[tile * 16 + col] : 0.0f;

    while (tile < ntiles) {
        const int tnext = tile + nwaves;
        float xn = 0.0f, on = 0.0f;
        if (tnext < ntiles) {
            xn = xscale * x[tnext * 16 + col];
            if (ACCUM) on = out[tnext * 16 + col];
        }

        // ---- layer 1 (fp32 VALU) ----
        f4v acc[4];
        #pragma unroll
        for (int t = 0; t < 4; ++t) {
            #pragma unroll
            for (int j = 0; j < 4; ++j) acc[t][j] = fmaf(w1p[t][j], xc, b1p[t][j]);
        }
        bf8v Bh[2], Bl[2];
        act_and_frags(acc, Bh, Bl);    // g1 -> fragments

        // ---- layer 2 ----
        f4v acc2[4];
        #pragma unroll
        for (int t = 0; t < 4; ++t) {
            f4v d = bias2[t];
            #pragma unroll
            for (int s = 0; s < 2; ++s) {
                d = MFMA(W2h[t][s], Bh[s], d);
                d = MFMA(W2h[t][s], Bl[s], d);
                d = MFMA(W2l[t][s], Bh[s], d);
            }
            acc2[t] = d;
        }
        act_and_frags(acc2, Bh, Bl);   // g2 -> fragments

        // ---- layer 3 ----
        #pragma unroll
        for (int t = 0; t < 4; ++t) {
            f4v d = bias3[t];
            #pragma unroll
            for (int s = 0; s < 2; ++s) {
                d = MFMA(W3h[t][s], Bh[s], d);
                d = MFMA(W3h[t][s], Bl[s], d);
                d = MFMA(W3l[t][s], Bh[s], d);
            }
            acc[t] = d;
        }
        #pragma unroll
        for (int t = 0; t < 4; ++t) {
            #pragma unroll
            for (int j = 0; j < 4; ++j) {
                float q = acc[t][j];
                float s = __sinf(q);
                acc[t][j] = fmaf(s, s, q);
            }
        }

        // ---- layer 4 ----
        float p = 0.0f;
        #pragma unroll
        for (int t = 0; t < 4; ++t) {
            #pragma unroll
            for (int j = 0; j < 4; ++j) p = fmaf(w4p[t][j], acc[t][j], p);
        }
        p += __shfl_xor(p, 16);
        p += __shfl_xor(p, 32);

        const float res = p + b4v + oc;
        if (lane < 16) out[tile * 16 + col] = res;

        tile = tnext; xc = xn; oc = on;
    }
}

extern "C" void kernel_launch(void* const* d_in, const int* in_sizes, int n_in,
                              void* d_out, int out_size, void* d_ws, size_t ws_size,
                              hipStream_t stream) {
    const float* x   = (const float*)d_in[0];
    const float* W1a = (const float*)d_in[1];
    const float* b1a = (const float*)d_in[2];
    const float* a1a = (const float*)d_in[3];
    const float* W2a = (const float*)d_in[4];
    const float* b2a = (const float*)d_in[5];
    const float* a2a = (const float*)d_in[6];
    const float* W3a = (const float*)d_in[7];
    const float* b3a = (const float*)d_in[8];
    const float* a3a = (const float*)d_in[9];
    const float* W4a = (const float*)d_in[10];
    const float* b4a = (const float*)d_in[11];
    const float* W1b = (const float*)d_in[12];
    const float* b1b = (const float*)d_in[13];
    const float* a1b = (const float*)d_in[14];
    const float* W2b = (const float*)d_in[15];
    const float* b2b = (const float*)d_in[16];
    const float* a2b = (const float*)d_in[17];
    const float* W3b = (const float*)d_in[18];
    const float* b3b = (const float*)d_in[19];
    const float* a3b = (const float*)d_in[20];
    const float* W4b = (const float*)d_in[21];
    const float* b4b = (const float*)d_in[22];

    const int n = in_sizes[0];
    float* out = (float*)d_out;

    mlp_branch<0><<<512, 256, 0, stream>>>(x, W1a, b1a, a1a, W2a, b2a, a2a,
                                           W3a, b3a, a3a, W4a, b4a,
                                           out, n, 1.0f);
    mlp_branch<1><<<512, 256, 0, stream>>>(x, W1b, b1b, a1b, W2b, b2b, a2b,
                                           W3b, b3b, a3b, W4b, b4b,
                                           out, n, 2.0f);
}